// Round 2
// baseline (300.871 us; speedup 1.0000x reference)
//
#include <hip/hip_runtime.h>

#define CIN 16
#define COUT 32
#define KK 9
#define NB 8
#define H 64
#define W 64
#define HW 4096
#define GROUPS 8
#define CPG (CIN / GROUPS)   // 2 input channels per block

// out[b,o,l] = sum_{i,k} w[i,o,k] * ( silu(v) + sum_n c[i,o,k,n]*T_n(tanh(v)) )
// Split over cin: blockIdx.y picks 2 input channels; partial sums accumulate
// into d_out via fp32 atomics (out is zeroed first each launch).
__global__ __launch_bounds__(256) void kan_conv_kernel(
    const float* __restrict__ x,   // (16,16,64,64)
    const float* __restrict__ w,   // (16,32,9,1)
    const float* __restrict__ c,   // (16,32,9,1,8)
    float* __restrict__ out)       // (16,32,64,64)
{
    const int pix = blockIdx.x * blockDim.x + threadIdx.x;  // 0..65535
    const int b  = pix >> 12;
    const int l  = pix & (HW - 1);
    const int y  = l >> 6;
    const int xx = l & 63;
    const int g  = blockIdx.y;      // cin group

    float acc[COUT];
#pragma unroll
    for (int o = 0; o < COUT; ++o) acc[o] = 0.f;

    for (int ci = 0; ci < CPG; ++ci) {
        const int i = g * CPG + ci;
        const float* xp = x + ((size_t)(b * CIN + i)) * HW;
#pragma unroll
        for (int kh = 0; kh < 3; ++kh) {
            const int yy = y + kh - 1;
            const bool yok = (yy >= 0) & (yy < H);
#pragma unroll
            for (int kw = 0; kw < 3; ++kw) {
                const int xk = xx + kw - 1;
                const bool ok = yok & (xk >= 0) & (xk < W);
                const float v = ok ? xp[yy * W + xk] : 0.f;
                const int k = kh * 3 + kw;

                // one exp serves both: p = e^{-v}
                // silu = v/(1+p); tanh = (1-p^2)/(1+p^2)
                const float p  = __expf(-v);
                const float p2 = p * p;
                const float s  = v * __builtin_amdgcn_rcpf(1.f + p);
                const float u  = (1.f - p2) * __builtin_amdgcn_rcpf(1.f + p2);

                float T[NB];
                T[0] = u;
                T[1] = 2.f * u * u - 1.f;
#pragma unroll
                for (int n = 2; n < NB; ++n) T[n] = 2.f * u * T[n - 1] - T[n - 2];

                // wave-uniform weight addresses -> scalar loads
                const float* wp = w + (size_t)(i * COUT) * KK + k;        // stride KK over o
                const float* cp = c + ((size_t)(i * COUT) * KK + k) * NB; // stride KK*NB over o
#pragma unroll
                for (int o = 0; o < COUT; ++o) {
                    float tmp = s;
#pragma unroll
                    for (int n = 0; n < NB; ++n)
                        tmp = fmaf(cp[(size_t)o * KK * NB + n], T[n], tmp);
                    acc[o] = fmaf(wp[(size_t)o * KK], tmp, acc[o]);
                }
            }
        }
    }

    float* op = out + (size_t)b * COUT * HW + l;
#pragma unroll
    for (int o = 0; o < COUT; ++o) atomicAdd(&op[(size_t)o * HW], acc[o]);
}

extern "C" void kernel_launch(void* const* d_in, const int* in_sizes, int n_in,
                              void* d_out, int out_size, void* d_ws, size_t ws_size,
                              hipStream_t stream) {
    const float* x = (const float*)d_in[0];
    const float* w = (const float*)d_in[1];
    const float* c = (const float*)d_in[2];
    float* out = (float*)d_out;

    hipMemsetAsync(out, 0, (size_t)out_size * sizeof(float), stream);

    dim3 grid(16 * HW / 256, GROUPS);   // 256 pixel-blocks x 8 cin-groups
    kan_conv_kernel<<<grid, 256, 0, stream>>>(x, w, c, out);
}

// Round 3
// 52.805 us; speedup vs baseline: 5.6978x; 5.6978x over previous
//
#include <hip/hip_runtime.h>

#define CIN 16
#define COUT 32
#define NB 8
#define HW 4096
#define PPW 66                 // padded image width (64 + ring)
#define PPA (66 * 66)          // 4356 padded pixels per (b)
#define KF 160                 // features per pixel: 16 ch * 10 (silu, T1..T8, zero-pad)
#define LDS_STRIDE 168         // 160 + 8 pad -> bank spread for ds_read_b128

typedef short bf16x8 __attribute__((ext_vector_type(8)));
typedef float f32x4 __attribute__((ext_vector_type(4)));

__device__ inline unsigned short f2bf(float f) {
    unsigned u = __builtin_bit_cast(unsigned, f);
    u += 0x7FFFu + ((u >> 16) & 1u);            // round-to-nearest-even
    return (unsigned short)(u >> 16);
}
__device__ inline unsigned pk(float a, float b) {
    return (unsigned)f2bf(a) | ((unsigned)f2bf(b) << 16);
}

// ---------- Pass 1: per-pixel features, bf16, K-contiguous, zero pad ring ----------
// g2[b][pp][160], pp over 66x66 padded grid. Interior: [silu, T1..T8, 0] per channel.
__global__ __launch_bounds__(128) void kan_feat(const float* __restrict__ x,
                                                unsigned short* __restrict__ g2) {
    const int t = blockIdx.x * 128 + threadIdx.x;
    if (t >= 16 * PPA) return;
    const int b  = t / PPA;
    const int pp = t - b * PPA;
    const int py = pp / PPW;
    const int px = pp - py * PPW;

    unsigned rw[KF / 2];
    const bool interior = (py >= 1) & (py <= 64) & (px >= 1) & (px <= 64);
    if (interior) {
        const int pix = (py - 1) * 64 + (px - 1);
#pragma unroll
        for (int i = 0; i < CIN; ++i) {
            const float v  = x[((size_t)(b * CIN + i)) * HW + pix];
            const float p  = __expf(-v);
            const float p2 = p * p;
            const float s  = v * __builtin_amdgcn_rcpf(1.f + p);           // silu
            const float u  = (1.f - p2) * __builtin_amdgcn_rcpf(1.f + p2); // tanh
            const float u2 = 2.f * u;
            const float t1 = u;
            const float t2 = u2 * u - 1.f;
            const float t3 = u2 * t2 - t1;
            const float t4 = u2 * t3 - t2;
            const float t5 = u2 * t4 - t3;
            const float t6 = u2 * t5 - t4;
            const float t7 = u2 * t6 - t5;
            const float t8 = u2 * t7 - t6;
            rw[i * 5 + 0] = pk(s, t1);
            rw[i * 5 + 1] = pk(t2, t3);
            rw[i * 5 + 2] = pk(t4, t5);
            rw[i * 5 + 3] = pk(t6, t7);
            rw[i * 5 + 4] = (unsigned)f2bf(t8);   // high half = 0 (pad feature)
        }
    } else {
#pragma unroll
        for (int j = 0; j < KF / 2; ++j) rw[j] = 0u;
    }
    uint4* dst = (uint4*)(g2 + (size_t)t * KF);   // 320B contiguous per thread
#pragma unroll
    for (int q = 0; q < KF / 8; ++q)
        dst[q] = make_uint4(rw[4 * q], rw[4 * q + 1], rw[4 * q + 2], rw[4 * q + 3]);
}

// ---------- Weight fold: Wf2[shift][o][160] bf16; n=0 -> w, n=1..8 -> w*c[n-1], n=9 -> 0 ----------
__global__ __launch_bounds__(256) void kan_wf(const float* __restrict__ w,
                                              const float* __restrict__ c,
                                              unsigned short* __restrict__ wf2) {
    const int t = blockIdx.x * 256 + threadIdx.x;
    if (t >= 9 * COUT * KF) return;
    const int f = t % KF;
    const int o = (t / KF) % COUT;
    const int k = t / (KF * COUT);        // shift index = kh*3+kw
    const int i = f / 10, n = f % 10;
    float val = 0.f;
    if (n != 9) {
        const float wv = w[(size_t)(i * COUT + o) * 9 + k];
        val = (n == 0) ? wv : wv * c[((size_t)(i * COUT + o) * 9 + k) * NB + (n - 1)];
    }
    wf2[t] = f2bf(val);
}

// ---------- Pass 2: implicit-im2col MFMA GEMM ----------
// Block = 4 waves = one image row (b,y); wave wv owns 16 pixels x0=wv*16.
// Per shift: stage Wf2[shift] (32x160) in LDS, 5 K-steps of mfma_f32_16x16x32_bf16.
__global__ __launch_bounds__(256) void kan_gemm(const unsigned short* __restrict__ g2,
                                                const unsigned short* __restrict__ wf2,
                                                float* __restrict__ out) {
    __shared__ unsigned short ldsA[COUT * LDS_STRIDE];
    const int blk  = blockIdx.x;          // 1024 = 16 b * 64 y
    const int b    = blk >> 6;
    const int y    = blk & 63;
    const int tid  = threadIdx.x;
    const int l    = tid & 63;
    const int wv   = tid >> 6;
    const int col  = l & 15;              // pixel within 16-wide fragment / A row
    const int quad = l >> 4;              // k-group
    const int x0   = wv * 16;

    f32x4 acc0 = {0.f, 0.f, 0.f, 0.f};
    f32x4 acc1 = {0.f, 0.f, 0.f, 0.f};

    for (int shift = 0; shift < 9; ++shift) {
        __syncthreads();                  // protect ldsA reads of previous shift
        for (int ch = tid; ch < 640; ch += 256) {      // 640 x 16B chunks = 32x160 bf16
            const int row = ch / 20;
            const int off = (ch % 20) * 8;
            *(uint4*)&ldsA[row * LDS_STRIDE + off] =
                *(const uint4*)&wf2[(size_t)(shift * COUT + row) * KF + off];
        }
        __syncthreads();

        const int dy = shift / 3 - 1, dx = shift % 3 - 1;
        const int pp = b * PPA + (y + 1 + dy) * PPW + (x0 + col + 1 + dx);
        const unsigned short* bb  = g2 + (size_t)pp * KF + quad * 8;
        const unsigned short* a0p = &ldsA[col * LDS_STRIDE + quad * 8];
        const unsigned short* a1p = &ldsA[(col + 16) * LDS_STRIDE + quad * 8];
#pragma unroll
        for (int st = 0; st < 5; ++st) {
            const bf16x8 bf = *(const bf16x8*)(bb + st * 32);
            const bf16x8 a0 = *(const bf16x8*)(a0p + st * 32);
            const bf16x8 a1 = *(const bf16x8*)(a1p + st * 32);
            acc0 = __builtin_amdgcn_mfma_f32_16x16x32_bf16(a0, bf, acc0, 0, 0, 0);
            acc1 = __builtin_amdgcn_mfma_f32_16x16x32_bf16(a1, bf, acc1, 0, 0, 0);
        }
    }

    // D: row o = quad*4 + r (+16 for acc1), col pixel = l&15
    float* op = out + (size_t)b * COUT * HW + y * 64 + x0 + col;
#pragma unroll
    for (int r = 0; r < 4; ++r) {
        op[(size_t)(quad * 4 + r) * HW]      = acc0[r];
        op[(size_t)(quad * 4 + r + 16) * HW] = acc1[r];
    }
}

extern "C" void kernel_launch(void* const* d_in, const int* in_sizes, int n_in,
                              void* d_out, int out_size, void* d_ws, size_t ws_size,
                              hipStream_t stream) {
    const float* x = (const float*)d_in[0];
    const float* w = (const float*)d_in[1];
    const float* c = (const float*)d_in[2];
    float* out = (float*)d_out;

    unsigned short* g2  = (unsigned short*)d_ws;                       // 16*4356*160 bf16 = 22.3 MB
    unsigned short* wf2 = (unsigned short*)((char*)d_ws + (size_t)16 * PPA * KF * 2);

    kan_wf<<<(9 * COUT * KF + 255) / 256, 256, 0, stream>>>(w, c, wf2);
    kan_feat<<<(16 * PPA + 127) / 128, 128, 0, stream>>>(x, g2);
    kan_gemm<<<1024, 256, 0, stream>>>(g2, wf2, out);
}